// Round 1
// baseline (514.005 us; speedup 1.0000x reference)
//
#include <hip/hip_runtime.h>

// BlockLinear: 64 independent GEMMs [4096x256] @ [256x256]^T + bias, fp32 in/out.
// Strategy: cast to bf16 on the fly, MFMA 16x16x32_bf16, fp32 accumulate.
// Memory-bound target ~554 MB @ ~6 TB/s ~= 95 us.

#define BATCH   4096
#define NBLK    64
#define KB_     256      // in_block (K)
#define OB_     256      // out_block (N)
#define BM      128      // M-tile
#define BK      64       // K-step
#define BKP     72       // padded LDS row stride (keeps 16B align, balanced banks)
#define NTHREADS 512     // 8 waves: 2 (M) x 4 (N), each wave 64x64

typedef __attribute__((ext_vector_type(8))) short bf16x8;   // 8 bf16 = 4 VGPRs
typedef __attribute__((ext_vector_type(4))) float f32x4;

__device__ __forceinline__ unsigned short f2bf(float f) {
    unsigned int u = __float_as_uint(f);
    u += 0x7FFFu + ((u >> 16) & 1u);   // round-to-nearest-even
    return (unsigned short)(u >> 16);
}

__global__ __launch_bounds__(NTHREADS, 4)
void blocklinear_kernel(const float* __restrict__ x,
                        const float* __restrict__ w,
                        const float* __restrict__ bias,
                        float* __restrict__ out)
{
    // wg%64 = block index -> all m-tiles of one block land on the same XCD
    // (round-robin i%8), keeping that block's 256KB weight slice L2-resident.
    const int wg  = blockIdx.x;
    const int blk = wg & 63;
    const int mt  = wg >> 6;          // 0..31
    const int m0  = mt * BM;

    const int tid  = threadIdx.x;
    const int lane = tid & 63;
    const int wave = tid >> 6;        // 0..7
    const int wm   = wave >> 2;       // 0..1  (M)
    const int wn   = wave & 3;        // 0..3  (N)

    __shared__ unsigned short Alds[BM * BKP];     // 18 KB
    __shared__ unsigned short Blds[OB_ * BKP];    // 36 KB

    f32x4 acc[4][4] = {};             // 64 fp32 accumulators / lane

    const float* xbase = x + (size_t)m0 * (NBLK * KB_) + (size_t)blk * KB_;
    const float* wbase = w + (size_t)blk * (OB_ * KB_);

    const int lrow = lane & 15;
    const int kq0  = (lane >> 4) << 3;   // quad*8

    for (int kb = 0; kb < KB_; kb += BK) {
        // ---- stage A: 128x64 fp32 -> bf16 LDS (2048 float4, 4/thread) ----
        #pragma unroll
        for (int i = 0; i < 4; i++) {
            int idx = tid + i * NTHREADS;
            int r = idx >> 4;             // 16 float4 per row
            int c = (idx & 15) << 2;
            float4 v = *(const float4*)(xbase + (size_t)r * (NBLK * KB_) + kb + c);
            ushort4 b;
            b.x = f2bf(v.x); b.y = f2bf(v.y); b.z = f2bf(v.z); b.w = f2bf(v.w);
            *(ushort4*)(&Alds[r * BKP + c]) = b;
        }
        // ---- stage B: 256x64 fp32 -> bf16 LDS (4096 float4, 8/thread) ----
        #pragma unroll
        for (int i = 0; i < 8; i++) {
            int idx = tid + i * NTHREADS;
            int r = idx >> 4;
            int c = (idx & 15) << 2;
            float4 v = *(const float4*)(wbase + r * KB_ + kb + c);
            ushort4 b;
            b.x = f2bf(v.x); b.y = f2bf(v.y); b.z = f2bf(v.z); b.w = f2bf(v.w);
            *(ushort4*)(&Blds[r * BKP + c]) = b;
        }
        __syncthreads();

        // ---- MFMA: 2 kk-steps x 16 MFMAs ----
        #pragma unroll
        for (int kk = 0; kk < BK; kk += 32) {
            bf16x8 af[4], bfr[4];
            int kq = kk + kq0;
            #pragma unroll
            for (int fm = 0; fm < 4; fm++)
                af[fm] = *(const bf16x8*)(&Alds[(wm * 64 + fm * 16 + lrow) * BKP + kq]);
            #pragma unroll
            for (int fn = 0; fn < 4; fn++)
                bfr[fn] = *(const bf16x8*)(&Blds[(wn * 64 + fn * 16 + lrow) * BKP + kq]);
            #pragma unroll
            for (int fm = 0; fm < 4; fm++)
                #pragma unroll
                for (int fn = 0; fn < 4; fn++)
                    acc[fm][fn] = __builtin_amdgcn_mfma_f32_16x16x32_bf16(
                        af[fm], bfr[fn], acc[fm][fn], 0, 0, 0);
        }
        __syncthreads();
    }

    // ---- epilogue: C/D layout col=lane&15, row=quad*4+reg ----
    const int quad = lane >> 4;
    #pragma unroll
    for (int fn = 0; fn < 4; fn++) {
        int col = wn * 64 + fn * 16 + lrow;
        float bv = bias[blk * OB_ + col];
        #pragma unroll
        for (int fm = 0; fm < 4; fm++) {
            #pragma unroll
            for (int r = 0; r < 4; r++) {
                int row = m0 + wm * 64 + fm * 16 + quad * 4 + r;
                out[(size_t)row * (NBLK * OB_) + blk * OB_ + col] = acc[fm][fn][r] + bv;
            }
        }
    }
}

extern "C" void kernel_launch(void* const* d_in, const int* in_sizes, int n_in,
                              void* d_out, int out_size, void* d_ws, size_t ws_size,
                              hipStream_t stream) {
    const float* x    = (const float*)d_in[0];
    const float* w    = (const float*)d_in[1];
    const float* bias = (const float*)d_in[2];
    float* out        = (float*)d_out;

    dim3 grid((BATCH / BM) * NBLK);   // 32 * 64 = 2048 WGs
    dim3 block(NTHREADS);
    blocklinear_kernel<<<grid, block, 0, stream>>>(x, w, bias, out);
}